// Round 11
// baseline (139.799 us; speedup 1.0000x reference)
//
#include <hip/hip_runtime.h>
#include <cstdint>

// 4-layer MLP: [B,64] -> 4 -> 8 -> 8 -> 32, sigmoid each layer. All f32.
//
// R8  (88us): direct-to-VGPR stride-128B loads, pair-split compute.
// R9  (145us): dense loads + LDS transpose BUT partial-sector stores ->
//      WRITE 375 MB (2.9x) -> entire regression explained by write flood.
// R10 (82us, best): R8 + LDS-staged dense stores (4x 1KB per wave).
// R11: A/B isolating the LOAD path: R10 with dense 1KB-per-instr loads ->
//      VGPR -> wave-private LDS transpose (swizzle conflict-free-optimal
//      both phases for b128: 8 lanes/4-bank-group, distinct addresses).
//      Out staging reuses the x-tile region (same-wave DS is in-order;
//      data deps force the lgkm wait first) -> LDS 34.6 KB, 4 blocks/CU.
//      If stride-load tag amplification is real: ~60-70us. If neutral:
//      loads exonerated, look at occupancy/latency next.

#define IN_DIM 64
#define OUT_DIM 32
#define THREADS 256
#define WAVES_PER_BLOCK 4
#define ROWS_PER_WAVE 32
#define ROWS_PER_BLOCK 128

__device__ __forceinline__ float fast_sigmoid(float z) {
    float e = __expf(-z);
    return __builtin_amdgcn_rcpf(1.0f + e);
}

// swizzled float4-slot within a 16-slot row, for chunk c of local row r.
// Write phase (4 rows x 16 chunks/instr) and read phase (32 rows x 2 halves,
// chunk h*8+j) both land 8 lanes per 4-bank group, distinct addresses =
// the conflict-free optimum for ds_*_b128 (8 rounds x 128 B).
__device__ __forceinline__ int swz(int r, int c) {
    return (c & 8) | ((((c ^ r) & 7) ^ ((c & 8) >> 1)) & 7);
}

__global__ __launch_bounds__(THREADS) void mlp4_kernel(
    const float* __restrict__ x,
    const float* __restrict__ W0, const float* __restrict__ b0,
    const float* __restrict__ W1, const float* __restrict__ b1,
    const float* __restrict__ W2, const float* __restrict__ b2,
    const float* __restrict__ W3, const float* __restrict__ b3,
    float* __restrict__ out, int batch)
{
    // Per-wave 8 KB x tile (32 rows x 16 float4), reused for out staging.
    __shared__ float4 sx[WAVES_PER_BLOCK * 512];
    __shared__ float sW0[4 * 64];
    __shared__ float sb0[4];
    __shared__ float sW1[8 * 4];
    __shared__ float sb1[8];
    __shared__ float sW2[8 * 8];
    __shared__ float sb2[8];
    __shared__ float sW3[32 * 8];
    __shared__ float sb3[32];

    const int tid  = threadIdx.x;
    const int wave = tid >> 6;
    const int lane = tid & 63;
    const int r    = lane >> 1;          // wave-local row 0..31
    const int h    = lane & 1;           // row half: cols [32h, 32h+32)

    const long long row0 = (long long)blockIdx.x * ROWS_PER_BLOCK
                         + (long long)wave * ROWS_PER_WAVE;

    // ---- Dense x loads FIRST: instr k reads 64 consecutive float4 = 1 KB.
    //      Latency hides under weight staging + barrier.
    const float4*   xg   = reinterpret_cast<const float4*>(x);
    const long long gmax = (long long)batch * 16 - 1;
    float4 xv[8];
    #pragma unroll
    for (int k = 0; k < 8; ++k) {
        long long g = row0 * 16 + (k << 6) + lane;
        if (g > gmax) g = gmax;          // tail-block clamp
        xv[k] = xg[g];
    }

    // ---- Stage weights/biases (~2.6 KB) ----
    sW0[tid] = W0[tid];
    sW3[tid] = W3[tid];
    if (tid < 64) sW2[tid] = W2[tid];
    if (tid < 32) { sW1[tid] = W1[tid]; sb3[tid] = b3[tid]; }
    if (tid < 8)  { sb1[tid] = b1[tid]; sb2[tid] = b2[tid]; }
    if (tid < 4)  { sb0[tid] = b0[tid]; }
    __syncthreads();

    if (row0 >= batch) return;   // wave-uniform (tail block only)

    // ---- Transpose via wave-private LDS: instr k holds rows 4k+(lane>>4),
    //      chunk lane&15 -> swizzled slot.
    const int wbase = wave << 9;
    #pragma unroll
    for (int k = 0; k < 8; ++k) {
        const int rl = (k << 2) | (lane >> 4);
        const int c  = lane & 15;
        sx[wbase + (rl << 4) + swz(rl, c)] = xv[k];
    }
    asm volatile("s_waitcnt lgkmcnt(0)" ::: "memory");
    __builtin_amdgcn_sched_barrier(0);

    // ---- Readback: lane 2r+h -> row r, chunks h*8+j ----
    float4 xr[8];
    #pragma unroll
    for (int j = 0; j < 8; ++j) {
        const int c = (h << 3) | j;
        xr[j] = sx[wbase + (r << 4) + swz(r, c)];
    }

    // ---- Layer 0: 64 -> 4, split across the lane pair ----
    const float4* w0v = reinterpret_cast<const float4*>(sW0);
    float h0[4];
    #pragma unroll
    for (int o = 0; o < 4; ++o) {
        float a = 0.f;
        #pragma unroll
        for (int k = 0; k < 8; ++k) {
            const float4 w = w0v[o * 16 + (h << 3) + k];   // 2-addr broadcast
            a = fmaf(xr[k].x, w.x, a);
            a = fmaf(xr[k].y, w.y, a);
            a = fmaf(xr[k].z, w.z, a);
            a = fmaf(xr[k].w, w.w, a);
        }
        const float sum = a + __shfl_xor(a, 1, 64);        // pair-reduce
        h0[o] = fast_sigmoid(sb0[o] + sum);
    }

    // ---- Layer 1: 4 -> 8 (pair-redundant; uniform b128 reads) ----
    const float4* w1v = reinterpret_cast<const float4*>(sW1);
    float h1[8];
    #pragma unroll
    for (int j = 0; j < 8; ++j) {
        const float4 w = w1v[j];
        float a = sb1[j];
        a = fmaf(h0[0], w.x, a); a = fmaf(h0[1], w.y, a);
        a = fmaf(h0[2], w.z, a); a = fmaf(h0[3], w.w, a);
        h1[j] = fast_sigmoid(a);
    }

    // ---- Layer 2: 8 -> 8 (pair-redundant; uniform b128 reads) ----
    const float4* w2v = reinterpret_cast<const float4*>(sW2);
    float h2[8];
    #pragma unroll
    for (int j = 0; j < 8; ++j) {
        const float4 wa = w2v[j * 2];
        const float4 wb = w2v[j * 2 + 1];
        float a = sb2[j];
        a = fmaf(h1[0], wa.x, a); a = fmaf(h1[1], wa.y, a);
        a = fmaf(h1[2], wa.z, a); a = fmaf(h1[3], wa.w, a);
        a = fmaf(h1[4], wb.x, a); a = fmaf(h1[5], wb.y, a);
        a = fmaf(h1[6], wb.z, a); a = fmaf(h1[7], wb.w, a);
        h2[j] = fast_sigmoid(a);
    }

    // ---- Layer 3: 8 -> 32, 16 outputs/lane -> swizzled LDS (region reuse;
    //      WAR-safe: same-wave DS is in-order and xr's lgkm wait happened) ----
    const float4* w3v = reinterpret_cast<const float4*>(sW3);
    #pragma unroll
    for (int q = 0; q < 4; ++q) {
        float o4[4];
        #pragma unroll
        for (int t = 0; t < 4; ++t) {
            const int oidx = (h << 4) + (q << 2) + t;
            const float4 wa = w3v[oidx * 2];               // 2-addr broadcast
            const float4 wb = w3v[oidx * 2 + 1];
            float a = sb3[oidx];
            a = fmaf(h2[0], wa.x, a); a = fmaf(h2[1], wa.y, a);
            a = fmaf(h2[2], wa.z, a); a = fmaf(h2[3], wa.w, a);
            a = fmaf(h2[4], wb.x, a); a = fmaf(h2[5], wb.y, a);
            a = fmaf(h2[6], wb.z, a); a = fmaf(h2[7], wb.w, a);
            o4[t] = fast_sigmoid(a);
        }
        const int slot = (r << 3) | (((h << 2) | q) ^ (r & 7));
        sx[wbase + slot] = make_float4(o4[0], o4[1], o4[2], o4[3]);
    }
    asm volatile("s_waitcnt lgkmcnt(0)" ::: "memory");
    __builtin_amdgcn_sched_barrier(0);   // wave-private region, no barrier

    // ---- Dense stores: instr m writes 64 consecutive float4 = 1 KB ----
    float4* og = reinterpret_cast<float4*>(out);
    const long long wout = row0 * 8;
    #pragma unroll
    for (int m = 0; m < 4; ++m) {
        const int rl = (m << 3) | (lane >> 3);
        const int cj = lane & 7;
        const float4 v = sx[wbase + (rl << 3) + (cj ^ (rl & 7))];
        if (row0 + rl < batch)
            og[wout + (m << 6) + lane] = v;
    }
}

extern "C" void kernel_launch(void* const* d_in, const int* in_sizes, int n_in,
                              void* d_out, int out_size, void* d_ws, size_t ws_size,
                              hipStream_t stream) {
    const float* x  = (const float*)d_in[0];
    const float* W0 = (const float*)d_in[1];
    const float* b0 = (const float*)d_in[2];
    const float* W1 = (const float*)d_in[3];
    const float* b1 = (const float*)d_in[4];
    const float* W2 = (const float*)d_in[5];
    const float* b2 = (const float*)d_in[6];
    const float* W3 = (const float*)d_in[7];
    const float* b3 = (const float*)d_in[8];
    float* out = (float*)d_out;

    const int batch  = in_sizes[0] / IN_DIM;  // 1,000,000
    const int blocks = (batch + ROWS_PER_BLOCK - 1) / ROWS_PER_BLOCK;

    mlp4_kernel<<<blocks, THREADS, 0, stream>>>(x, W0, b0, W1, b1,
                                                W2, b2, W3, b3, out, batch);
}

// Round 12
// 100.482 us; speedup vs baseline: 1.3913x; 1.3913x over previous
//
#include <hip/hip_runtime.h>
#include <cstdint>

// 4-layer MLP: [B,64] -> 4 -> 8 -> 8 -> 32, sigmoid each layer. All f32.
//
// Measured ladder: R1 145 (1 row/thread, VGPR=32 -> ~2 loads in flight),
// R3 95 (global_load_lds), R8 88 (stride loads, pair-split), R10 82 (best),
// R9/R11 140-145 (dense loads + LDS transpose — dead end; +58us regardless
// of store path; WRITE 375 MB tracked the LOAD pattern, not stores).
// Only-ever-ideal WRITE (125 MB): R1/R2's per-lane contiguous 128 B row
// stores. R1's slowness was load serialization, not its access pattern.
//
// R12 = "R1 done right": one lane = one row.
//   loads:  16 contiguous dwordx4 per lane (256 B), issued BEFORE weight
//           staging; __syncthreads' implicit vmcnt(0) drain hides latency.
//           o-major L0 consumption keeps all 16 dests live -> all in flight.
//   compute: full row per lane; no shfl, no redundancy, no x-LDS.
//   stores: 8 contiguous float4 per lane (the measured WRITE~=1x pattern).
//   weights: LDS, uniform b128 broadcasts (bank-free).

#define IN_DIM 64
#define OUT_DIM 32
#define THREADS 256

__device__ __forceinline__ float fast_sigmoid(float z) {
    float e = __expf(-z);
    return __builtin_amdgcn_rcpf(1.0f + e);
}

__global__ __launch_bounds__(THREADS) void mlp4_kernel(
    const float* __restrict__ x,
    const float* __restrict__ W0, const float* __restrict__ b0,
    const float* __restrict__ W1, const float* __restrict__ b1,
    const float* __restrict__ W2, const float* __restrict__ b2,
    const float* __restrict__ W3, const float* __restrict__ b3,
    float* __restrict__ out, int batch)
{
    // Weights/biases only (~2.6 KB LDS).
    __shared__ float sW0[4 * 64];
    __shared__ float sb0[4];
    __shared__ float sW1[8 * 4];
    __shared__ float sb1[8];
    __shared__ float sW2[8 * 8];
    __shared__ float sb2[8];
    __shared__ float sW3[32 * 8];
    __shared__ float sb3[32];

    const int tid = threadIdx.x;
    const long long row   = (long long)blockIdx.x * THREADS + tid;
    const bool      valid = row < batch;
    const long long lrow  = valid ? row : (long long)(batch - 1);

    // ---- Issue ALL 16 row loads first (256 B contiguous per lane).
    //      Latency hides under weight staging + the barrier's vmcnt drain.
    const float4* xp = reinterpret_cast<const float4*>(x + lrow * IN_DIM);
    float4 xv[16];
    #pragma unroll
    for (int k = 0; k < 16; ++k) xv[k] = xp[k];

    // ---- Stage weights/biases (independent of x loads) ----
    sW0[tid] = W0[tid];
    sW3[tid] = W3[tid];
    if (tid < 64) sW2[tid] = W2[tid];
    if (tid < 32) { sW1[tid] = W1[tid]; sb3[tid] = b3[tid]; }
    if (tid < 8)  { sb1[tid] = b1[tid]; sb2[tid] = b2[tid]; }
    if (tid < 4)  { sb0[tid] = b0[tid]; }
    __syncthreads();   // drains vmcnt too: x is in registers after this

    // ---- Layer 0: 64 -> 4, o-major (keeps all 16 xv live) ----
    const float4* w0v = reinterpret_cast<const float4*>(sW0);
    float h0[4];
    #pragma unroll
    for (int o = 0; o < 4; ++o) {
        float a = sb0[o];
        #pragma unroll
        for (int k = 0; k < 16; ++k) {
            const float4 w = w0v[o * 16 + k];   // uniform b128 broadcast
            a = fmaf(xv[k].x, w.x, a);
            a = fmaf(xv[k].y, w.y, a);
            a = fmaf(xv[k].z, w.z, a);
            a = fmaf(xv[k].w, w.w, a);
        }
        h0[o] = fast_sigmoid(a);
    }

    // ---- Layer 1: 4 -> 8 (uniform b128 reads) ----
    const float4* w1v = reinterpret_cast<const float4*>(sW1);
    float h1[8];
    #pragma unroll
    for (int j = 0; j < 8; ++j) {
        const float4 w = w1v[j];
        float a = sb1[j];
        a = fmaf(h0[0], w.x, a); a = fmaf(h0[1], w.y, a);
        a = fmaf(h0[2], w.z, a); a = fmaf(h0[3], w.w, a);
        h1[j] = fast_sigmoid(a);
    }

    // ---- Layer 2: 8 -> 8 (uniform b128 reads) ----
    const float4* w2v = reinterpret_cast<const float4*>(sW2);
    float h2[8];
    #pragma unroll
    for (int j = 0; j < 8; ++j) {
        const float4 wa = w2v[j * 2];
        const float4 wb = w2v[j * 2 + 1];
        float a = sb2[j];
        a = fmaf(h1[0], wa.x, a); a = fmaf(h1[1], wa.y, a);
        a = fmaf(h1[2], wa.z, a); a = fmaf(h1[3], wa.w, a);
        a = fmaf(h1[4], wb.x, a); a = fmaf(h1[5], wb.y, a);
        a = fmaf(h1[6], wb.z, a); a = fmaf(h1[7], wb.w, a);
        h2[j] = fast_sigmoid(a);
    }

    // ---- Layer 3: 8 -> 32; 8 contiguous float4 stores per lane ----
    if (valid) {
        const float4* w3v = reinterpret_cast<const float4*>(sW3);
        float4* op = reinterpret_cast<float4*>(out + (size_t)row * OUT_DIM);
        #pragma unroll
        for (int q = 0; q < 8; ++q) {
            float o4[4];
            #pragma unroll
            for (int t = 0; t < 4; ++t) {
                const int oidx = (q << 2) + t;
                const float4 wa = w3v[oidx * 2];   // uniform broadcasts
                const float4 wb = w3v[oidx * 2 + 1];
                float a = sb3[oidx];
                a = fmaf(h2[0], wa.x, a); a = fmaf(h2[1], wa.y, a);
                a = fmaf(h2[2], wa.z, a); a = fmaf(h2[3], wa.w, a);
                a = fmaf(h2[4], wb.x, a); a = fmaf(h2[5], wb.y, a);
                a = fmaf(h2[6], wb.z, a); a = fmaf(h2[7], wb.w, a);
                o4[t] = fast_sigmoid(a);
            }
            op[q] = make_float4(o4[0], o4[1], o4[2], o4[3]);
        }
    }
}

extern "C" void kernel_launch(void* const* d_in, const int* in_sizes, int n_in,
                              void* d_out, int out_size, void* d_ws, size_t ws_size,
                              hipStream_t stream) {
    const float* x  = (const float*)d_in[0];
    const float* W0 = (const float*)d_in[1];
    const float* b0 = (const float*)d_in[2];
    const float* W1 = (const float*)d_in[3];
    const float* b1 = (const float*)d_in[4];
    const float* W2 = (const float*)d_in[5];
    const float* b2 = (const float*)d_in[6];
    const float* W3 = (const float*)d_in[7];
    const float* b3 = (const float*)d_in[8];
    float* out = (float*)d_out;

    const int batch  = in_sizes[0] / IN_DIM;  // 1,000,000
    const int blocks = (batch + THREADS - 1) / THREADS;

    mlp4_kernel<<<blocks, THREADS, 0, stream>>>(x, W0, b0, W1, b1,
                                                W2, b2, W3, b3, out, batch);
}

// Round 13
// 64.367 us; speedup vs baseline: 2.1719x; 1.5611x over previous
//
#include <hip/hip_runtime.h>
#include <cstdint>

// 4-layer MLP: [B,64] -> 4 -> 8 -> 8 -> 32, sigmoid each layer. All f32.
//
// Ladder: R1 145, R3 95, R8 88, R10 82 (best), R9/R11 ~140 (LDS-transpose
// dead end), R12 100 (full-row/lane: VGPR+footprint cost).
// FETCH ledger: normal streaming stores -> FETCH 250 MB (out-writes evict x
// from L3 every replay). R7's NT stores -> FETCH 125 MB (x half-resident)
// but its 16B-scatter pattern + NT = partial-sector writes (WRITE 205 MB).
// R13 = R10 + NT on the DENSE 1 KB store instrs (8 full lines/instr, one
// instruction per line -> no partial-sector risk, L3 no-allocate preserved).
// Single-variable A/B vs R10.

#define IN_DIM 64
#define OUT_DIM 32
#define THREADS 256
#define WAVES_PER_BLOCK 4
#define ROWS_PER_WAVE 32
#define ROWS_PER_BLOCK 128

typedef float v4f __attribute__((ext_vector_type(4)));

__device__ __forceinline__ float fast_sigmoid(float z) {
    float e = __expf(-z);
    return __builtin_amdgcn_rcpf(1.0f + e);
}

__global__ __launch_bounds__(THREADS) void mlp4_kernel(
    const float* __restrict__ x,
    const float* __restrict__ W0, const float* __restrict__ b0,
    const float* __restrict__ W1, const float* __restrict__ b1,
    const float* __restrict__ W2, const float* __restrict__ b2,
    const float* __restrict__ W3, const float* __restrict__ b3,
    float* __restrict__ out, int batch)
{
    // Out staging: 4 waves x 256 float4 (4 KB each) = 16 KB, wave-private.
    __shared__ float4 sOut[WAVES_PER_BLOCK * 256];
    // Weights/biases (~2.6 KB).
    __shared__ float sW0[4 * 64];
    __shared__ float sb0[4];
    __shared__ float sW1[8 * 4];
    __shared__ float sb1[8];
    __shared__ float sW2[8 * 8];
    __shared__ float sb2[8];
    __shared__ float sW3[32 * 8];
    __shared__ float sb3[32];

    const int tid  = threadIdx.x;
    const int wave = tid >> 6;
    const int lane = tid & 63;
    const int r    = lane >> 1;          // wave-local row 0..31
    const int h    = lane & 1;           // row half: cols [32h, 32h+32)

    const long long row0 = (long long)blockIdx.x * ROWS_PER_BLOCK
                         + (long long)wave * ROWS_PER_WAVE;
    const long long row  = row0 + r;
    const long long lrow = (row < batch) ? row : (long long)(batch - 1);

    // ---- x loads FIRST: 8 independent dwordx4 (128 B contiguous per lane);
    //      latency hides under weight staging + barrier.
    const float4* xp = reinterpret_cast<const float4*>(x + lrow * IN_DIM) + (h << 3);
    float4 xv[8];
    #pragma unroll
    for (int k = 0; k < 8; ++k) xv[k] = xp[k];

    // ---- Stage weights/biases ----
    sW0[tid] = W0[tid];
    sW3[tid] = W3[tid];
    if (tid < 64) sW2[tid] = W2[tid];
    if (tid < 32) { sW1[tid] = W1[tid]; sb3[tid] = b3[tid]; }
    if (tid < 8)  { sb1[tid] = b1[tid]; sb2[tid] = b2[tid]; }
    if (tid < 4)  { sb0[tid] = b0[tid]; }
    __syncthreads();

    if (row0 >= batch) return;   // wave-uniform (tail block only)

    // ---- Layer 0: 64 -> 4, split across the lane pair ----
    const float4* w0v = reinterpret_cast<const float4*>(sW0);
    float h0[4];
    #pragma unroll
    for (int o = 0; o < 4; ++o) {
        float a = 0.f;
        #pragma unroll
        for (int k = 0; k < 8; ++k) {
            const float4 w = w0v[o * 16 + (h << 3) + k];   // 2-addr broadcast
            a = fmaf(xv[k].x, w.x, a);
            a = fmaf(xv[k].y, w.y, a);
            a = fmaf(xv[k].z, w.z, a);
            a = fmaf(xv[k].w, w.w, a);
        }
        const float sum = a + __shfl_xor(a, 1, 64);        // pair-reduce
        h0[o] = fast_sigmoid(sb0[o] + sum);
    }

    // ---- Layer 1: 4 -> 8 (pair-redundant; uniform b128 reads) ----
    const float4* w1v = reinterpret_cast<const float4*>(sW1);
    float h1[8];
    #pragma unroll
    for (int j = 0; j < 8; ++j) {
        const float4 w = w1v[j];
        float a = sb1[j];
        a = fmaf(h0[0], w.x, a); a = fmaf(h0[1], w.y, a);
        a = fmaf(h0[2], w.z, a); a = fmaf(h0[3], w.w, a);
        h1[j] = fast_sigmoid(a);
    }

    // ---- Layer 2: 8 -> 8 (pair-redundant; uniform b128 reads) ----
    const float4* w2v = reinterpret_cast<const float4*>(sW2);
    float h2[8];
    #pragma unroll
    for (int j = 0; j < 8; ++j) {
        const float4 wa = w2v[j * 2];
        const float4 wb = w2v[j * 2 + 1];
        float a = sb2[j];
        a = fmaf(h1[0], wa.x, a); a = fmaf(h1[1], wa.y, a);
        a = fmaf(h1[2], wa.z, a); a = fmaf(h1[3], wa.w, a);
        a = fmaf(h1[4], wb.x, a); a = fmaf(h1[5], wb.y, a);
        a = fmaf(h1[6], wb.z, a); a = fmaf(h1[7], wb.w, a);
        h2[j] = fast_sigmoid(a);
    }

    // ---- Layer 3: 8 -> 32, 16 outputs per lane -> swizzled LDS ----
    const float4* w3v  = reinterpret_cast<const float4*>(sW3);
    const int     obase = wave << 8;     // 256 float4 slots per wave
    #pragma unroll
    for (int q = 0; q < 4; ++q) {
        float o4[4];
        #pragma unroll
        for (int t = 0; t < 4; ++t) {
            const int oidx = (h << 4) + (q << 2) + t;
            const float4 wa = w3v[oidx * 2];               // 2-addr broadcast
            const float4 wb = w3v[oidx * 2 + 1];
            float a = sb3[oidx];
            a = fmaf(h2[0], wa.x, a); a = fmaf(h2[1], wa.y, a);
            a = fmaf(h2[2], wa.z, a); a = fmaf(h2[3], wa.w, a);
            a = fmaf(h2[4], wb.x, a); a = fmaf(h2[5], wb.y, a);
            a = fmaf(h2[6], wb.z, a); a = fmaf(h2[7], wb.w, a);
            o4[t] = fast_sigmoid(a);
        }
        const int slot = (r << 3) | (((h << 2) | q) ^ (r & 7));
        sOut[obase + slot] = make_float4(o4[0], o4[1], o4[2], o4[3]);
    }
    asm volatile("s_waitcnt lgkmcnt(0)" ::: "memory");
    __builtin_amdgcn_sched_barrier(0);   // wave-private region, no barrier

    // ---- Dense NONTEMPORAL stores: instr m writes 64 consecutive float4
    //      = 1 KB = 8 full 128 B lines; NT (no L3 allocate) preserves x's
    //      L3 residency across replays without partial-sector risk.
    v4f* og = reinterpret_cast<v4f*>(out);
    const long long wout = row0 * 8;     // wave's first out float4
    #pragma unroll
    for (int m = 0; m < 4; ++m) {
        const int rl = (m << 3) | (lane >> 3);
        const int cj = lane & 7;
        const float4 v = sOut[obase + (rl << 3) + (cj ^ (rl & 7))];
        if (row0 + rl < batch) {
            v4f vv = {v.x, v.y, v.z, v.w};
            __builtin_nontemporal_store(vv, og + wout + (m << 6) + lane);
        }
    }
}

extern "C" void kernel_launch(void* const* d_in, const int* in_sizes, int n_in,
                              void* d_out, int out_size, void* d_ws, size_t ws_size,
                              hipStream_t stream) {
    const float* x  = (const float*)d_in[0];
    const float* W0 = (const float*)d_in[1];
    const float* b0 = (const float*)d_in[2];
    const float* W1 = (const float*)d_in[3];
    const float* b1 = (const float*)d_in[4];
    const float* W2 = (const float*)d_in[5];
    const float* b2 = (const float*)d_in[6];
    const float* W3 = (const float*)d_in[7];
    const float* b3 = (const float*)d_in[8];
    float* out = (float*)d_out;

    const int batch  = in_sizes[0] / IN_DIM;  // 1,000,000
    const int blocks = (batch + ROWS_PER_BLOCK - 1) / ROWS_PER_BLOCK;

    mlp4_kernel<<<blocks, THREADS, 0, stream>>>(x, W0, b0, W1, b1,
                                                W2, b2, W3, b3, out, batch);
}